// Round 1
// baseline (189.869 us; speedup 1.0000x reference)
//
#include <hip/hip_runtime.h>

#define NBATCH 8192
#define HDIM   64
#define SEQ    180
#define MT     16     // batch rows per chain
#define NC     2      // independent chains per block (interleaved in time)
#define SB     72     // bf16 LDS row stride: 144 B, 16B-aligned
#define XSP    100    // xs prologue row stride (floats)

typedef __bf16 bf16x8 __attribute__((ext_vector_type(8)));
typedef __bf16 bf16x4 __attribute__((ext_vector_type(4)));
typedef float  f32x4  __attribute__((ext_vector_type(4)));

#define L2E 1.44269504088896340736f

__device__ __forceinline__ float tanh_f(float x) {
    float e = __builtin_amdgcn_exp2f((2.0f * L2E) * x);
    return 1.0f - 2.0f * __builtin_amdgcn_rcpf(1.0f + e);
}

#define MFMA __builtin_amdgcn_mfma_f32_16x16x32_bf16

// GRU gate epilogue for one chain: identical math/op-order to the proven R15
// kernel (fp32 carry, bf16 state publish). Returns new h, writes bf16x4 state.
__device__ __forceinline__ f32x4 gru_epi(f32x4 aR, f32x4 aZ, f32x4 aN,
        f32x4 cR4, f32x4 cZ4, f32x4 bn4, f32x4 cN4, f32x4 one4,
        f32x4 hprev, __bf16* Nh, int wboff) {
    f32x4 tR = aR * (-L2E) + cR4;
    f32x4 tZ = aZ * (-L2E) + cZ4;
    f32x4 eR, eZ;
#pragma unroll
    for (int r = 0; r < 4; ++r) {
        eR[r] = __builtin_amdgcn_exp2f(tR[r]);
        eZ[r] = __builtin_amdgcn_exp2f(tZ[r]);
    }
    eR = eR + one4;
    eZ = eZ + one4;
    f32x4 rg, zg;
#pragma unroll
    for (int r = 0; r < 4; ++r) {
        rg[r] = __builtin_amdgcn_rcpf(eR[r]);
        zg[r] = __builtin_amdgcn_rcpf(eZ[r]);
    }
    f32x4 mm = aN + bn4;
    f32x4 tN = (rg * mm) * (2.0f * L2E) + cN4;
    f32x4 eN;
#pragma unroll
    for (int r = 0; r < 4; ++r) eN[r] = __builtin_amdgcn_exp2f(tN[r]);
    eN = eN + one4;
    f32x4 dd;
#pragma unroll
    for (int r = 0; r < 4; ++r) dd[r] = __builtin_amdgcn_rcpf(eN[r]);
    f32x4 ng = dd * (-2.0f) + one4;
    f32x4 hn = zg * (hprev - ng) + ng;   // exact fp32 carry
    bf16x4 hp;
#pragma unroll
    for (int r = 0; r < 4; ++r) hp[r] = (__bf16)hn[r];
    *(bf16x4*)(Nh + wboff) = hp;         // one ds_write_b64
    return hn;
}

// R16 = R15 core + dual-chain interleave: 1 block/CU (grid 256), each block
// owns TWO independent 16-row GRU chains. Both chains advance in one
// superstep under a SINGLE barrier: chain B's MFMAs/epilogue fill chain A's
// trans-pipe and LDS-roundtrip latency (and vice versa). Halves barriers per
// chain-step, gives every wave a whole SIMD (4 waves -> 4 SIMDs), and removes
// the cross-block s_sleep anti-phase hack. Weights/biases are per-column and
// shared between chains; only hprev duplicates.
__global__ __launch_bounds__(256) void gru_all(
        const float* __restrict__ z, const int* __restrict__ labels,
        const float* __restrict__ embed_w, const float* __restrict__ fc_w,
        const float* __restrict__ fc_b, const float* __restrict__ w_hh,
        const float* __restrict__ b_ih, const float* __restrict__ b_hh,
        const float* __restrict__ out_w, const float* __restrict__ out_b,
        float* __restrict__ out) {
    __shared__ __align__(16) __bf16 hbuf[NC][2][MT * SB];  // [chain][buf]
    __shared__ __align__(16) float  xs[NC * MT * XSP];     // h0 input [z|embed]

    const int t = threadIdx.x;
    const int w = t >> 6;          // wave 0..3
    const int l = t & 63;
    const int q = l >> 4;          // quad 0..3
    const int n16 = l & 15;
    const int jg = 16 * w + n16;   // W row this lane loads (A-frag m-index)
    const int jb = 16 * w + 4 * q; // first of the 4 h-cols this lane epilogues
    const int bbase = blockIdx.x * (NC * MT);

    // ---- prologue A: stage x = [z, embed(labels)] for 32 rows into LDS ----
    for (int c = t; c < NC * MT * 24; c += 256) {   // 24 f32x4 chunks per row
        int m = c / 24, kk = (c % 24) * 4;
        f32x4 v;
        if (kk < 32) v = *(const f32x4*)(z + (size_t)(bbase + m) * 32 + kk);
        else         v = *(const f32x4*)(embed_w + labels[bbase + m] * 64 + (kk - 32));
        *(f32x4*)(xs + m * XSP + kk) = v;
    }

    // ---- persistent w_hh fragments, plain bf16 (MFMA A-operands) ----
    // A[m = n16][k = q*8+j + 32ks] = w_hh[g*64 + jg][k]  (shared by chains)
    bf16x8 whi[3][2];
#pragma unroll
    for (int g = 0; g < 3; ++g) {
        const float* pr = w_hh + (g * 64 + jg) * HDIM;
#pragma unroll
        for (int ks = 0; ks < 2; ++ks) {
            const float* p = pr + ks * 32 + q * 8;
            f32x4 va = *(const f32x4*)(p);
            f32x4 vb = *(const f32x4*)(p + 4);
#pragma unroll
            for (int j2 = 0; j2 < 4; ++j2) {
                whi[g][ks][j2]     = (__bf16)va[j2];
                whi[g][ks][4 + j2] = (__bf16)vb[j2];
            }
        }
    }

    // ---- output-head A fragments: A[m=n16][k] = out_w[n16][k] (n16<2 live) --
    bf16x8 obhi[2];
#pragma unroll
    for (int ks = 0; ks < 2; ++ks) {
        f32x4 va = {0.f, 0.f, 0.f, 0.f}, vb = {0.f, 0.f, 0.f, 0.f};
        if (n16 < 2) {
            va = *(const f32x4*)(out_w + n16 * 64 + ks * 32 + q * 8);
            vb = *(const f32x4*)(out_w + n16 * 64 + ks * 32 + q * 8 + 4);
        }
#pragma unroll
        for (int j2 = 0; j2 < 4; ++j2) {
            obhi[ks][j2]     = (__bf16)va[j2];
            obhi[ks][4 + j2] = (__bf16)vb[j2];
        }
    }
    const f32x4 obias = (q == 0) ? f32x4{out_b[0], out_b[1], 0.f, 0.f}
                                 : f32x4{0.f, 0.f, 0.f, 0.f};
    const f32x4 kZ = {0.f, 0.f, 0.f, 0.f};
    const f32x4 one4 = {1.f, 1.f, 1.f, 1.f};

    // every wave computes heads (identical streams, no straggler); each
    // stores only its 4 rows per chain
    const bool ostorer = (q == 0) && ((n16 >> 2) == w);

    // per-lane gate constants over the lane's 4 cols jb..jb+3 (chain-shared)
    const f32x4 bihR = *(const f32x4*)(b_ih + jb);
    const f32x4 bhhR = *(const f32x4*)(b_hh + jb);
    const f32x4 bihZ = *(const f32x4*)(b_ih + 64 + jb);
    const f32x4 bhhZ = *(const f32x4*)(b_hh + 64 + jb);
    const f32x4 cR4 = (bihR + bhhR) * (-L2E);
    const f32x4 cZ4 = (bihZ + bhhZ) * (-L2E);
    const f32x4 bn4 = *(const f32x4*)(b_hh + 128 + jb);
    const f32x4 cN4 = (*(const f32x4*)(b_ih + 128 + jb)) * (2.0f * L2E);

    const int rdoff = n16 * SB + q * 8;    // h B-frag offset (16B-aligned)
    const int wboff = n16 * SB + jb;       // state-write offset (8B-aligned)
    float* opbA = out + (size_t)(bbase + n16) * (SEQ * 2);
    float* opbB = out + (size_t)(bbase + MT + n16) * (SEQ * 2);

    __syncthreads();   // xs ready

    // ---- prologue B: h0 = tanh(fc_b + fc_w . x) for BOTH chains; the fc_w
    // row loads are shared (2 fma4 per load) ----
    f32x4 hpA, hpB;
    {
        f32x4 aA = *(const f32x4*)(fc_b + jb);
        f32x4 aB = aA;
        for (int kc = 0; kc < 24; ++kc) {
            f32x4 xvA = *(const f32x4*)(xs + n16 * XSP + kc * 4);
            f32x4 xvB = *(const f32x4*)(xs + (MT + n16) * XSP + kc * 4);
#pragma unroll
            for (int r = 0; r < 4; ++r) {
                f32x4 wv = *(const f32x4*)(fc_w + (size_t)(jb + r) * 96 + kc * 4);
                aA[r] += wv[0] * xvA[0] + wv[1] * xvA[1] + wv[2] * xvA[2] + wv[3] * xvA[3];
                aB[r] += wv[0] * xvB[0] + wv[1] * xvB[1] + wv[2] * xvB[2] + wv[3] * xvB[3];
            }
        }
        bf16x4 ha, hb;
#pragma unroll
        for (int r = 0; r < 4; ++r) {
            hpA[r] = tanh_f(aA[r]); ha[r] = (__bf16)hpA[r];
            hpB[r] = tanh_f(aB[r]); hb[r] = (__bf16)hpB[r];
        }
        *(bf16x4*)(hbuf[0][0] + wboff) = ha;
        *(bf16x4*)(hbuf[1][0] + wboff) = hb;
    }
    __syncthreads();   // state 0 published in buf 0 for both chains

    // ---- main loop: 180 supersteps, ONE barrier each, both chains/step ----
    for (int u = 0; u < SEQ / 2; ++u) {
#pragma unroll
        for (int s = 0; s < 2; ++s) {
            const __bf16* HA = hbuf[0][s];
            __bf16*       NA = hbuf[0][s ^ 1];
            const __bf16* HB = hbuf[1][s];
            __bf16*      NhB = hbuf[1][s ^ 1];

            // h B-frags of state i = 2u+s for both chains
            bf16x8 a0 = *(const bf16x8*)(HA + rdoff);
            bf16x8 a1 = *(const bf16x8*)(HA + rdoff + 32);
            bf16x8 c0 = *(const bf16x8*)(HB + rdoff);
            bf16x8 c1 = *(const bf16x8*)(HB + rdoff + 32);

            // gates: G^T = W·h^T, 2-deep chain per gate, chains independent
            f32x4 ArA = MFMA(whi[0][0], a0, kZ, 0, 0, 0);
            f32x4 AzA = MFMA(whi[1][0], a0, kZ, 0, 0, 0);
            f32x4 AnA = MFMA(whi[2][0], a0, kZ, 0, 0, 0);
            f32x4 ArB = MFMA(whi[0][0], c0, kZ, 0, 0, 0);
            f32x4 AzB = MFMA(whi[1][0], c0, kZ, 0, 0, 0);
            f32x4 AnB = MFMA(whi[2][0], c0, kZ, 0, 0, 0);
            ArA = MFMA(whi[0][1], a1, ArA, 0, 0, 0);
            AzA = MFMA(whi[1][1], a1, AzA, 0, 0, 0);
            AnA = MFMA(whi[2][1], a1, AnA, 0, 0, 0);
            ArB = MFMA(whi[0][1], c1, ArB, 0, 0, 0);
            AzB = MFMA(whi[1][1], c1, AzB, 0, 0, 0);
            AnB = MFMA(whi[2][1], c1, AnB, 0, 0, 0);

            // output heads on state i -> out row i-1 (store early, drains
            // well before the barrier's vmcnt wait)
            {
                f32x4 oA = obias;
                oA = MFMA(obhi[0], a0, oA, 0, 0, 0);
                oA = MFMA(obhi[1], a1, oA, 0, 0, 0);
                f32x4 oB = obias;
                oB = MFMA(obhi[0], c0, oB, 0, 0, 0);
                oB = MFMA(obhi[1], c1, oB, 0, 0, 0);
                if ((u | s) != 0 && ostorer) {
                    *(float2*)(opbA + (4 * u + 2 * s - 2)) = make_float2(oA[0], oA[1]);
                    *(float2*)(opbB + (4 * u + 2 * s - 2)) = make_float2(oB[0], oB[1]);
                }
            }

            hpA = gru_epi(ArA, AzA, AnA, cR4, cZ4, bn4, cN4, one4, hpA, NA,  wboff);
            hpB = gru_epi(ArB, AzB, AnB, cR4, cZ4, bn4, cN4, one4, hpB, NhB, wboff);

            __syncthreads();   // states i+1 (both chains) published
        }
    }

    // final output: row 179 from state 180 (in buf 0 of each chain)
    {
        bf16x8 a0 = *(const bf16x8*)(hbuf[0][0] + rdoff);
        bf16x8 a1 = *(const bf16x8*)(hbuf[0][0] + rdoff + 32);
        bf16x8 c0 = *(const bf16x8*)(hbuf[1][0] + rdoff);
        bf16x8 c1 = *(const bf16x8*)(hbuf[1][0] + rdoff + 32);
        f32x4 oA = obias;
        oA = MFMA(obhi[0], a0, oA, 0, 0, 0);
        oA = MFMA(obhi[1], a1, oA, 0, 0, 0);
        f32x4 oB = obias;
        oB = MFMA(obhi[0], c0, oB, 0, 0, 0);
        oB = MFMA(obhi[1], c1, oB, 0, 0, 0);
        if (ostorer) {
            *(float2*)(opbA + (SEQ - 1) * 2) = make_float2(oA[0], oA[1]);
            *(float2*)(opbB + (SEQ - 1) * 2) = make_float2(oB[0], oB[1]);
        }
    }
}

extern "C" void kernel_launch(void* const* d_in, const int* in_sizes, int n_in,
                              void* d_out, int out_size, void* d_ws, size_t ws_size,
                              hipStream_t stream) {
    (void)in_sizes; (void)n_in; (void)out_size; (void)d_ws; (void)ws_size;
    const float* z       = (const float*)d_in[0];
    const int*   labels  = (const int*)d_in[1];
    const float* embed_w = (const float*)d_in[2];
    const float* fc_w    = (const float*)d_in[3];
    const float* fc_b    = (const float*)d_in[4];
    // d_in[5] = w_ih: unused (GRU input is all zeros; b_ih carries the effect)
    const float* w_hh    = (const float*)d_in[6];
    const float* b_ih    = (const float*)d_in[7];
    const float* b_hh    = (const float*)d_in[8];
    const float* out_w   = (const float*)d_in[9];
    const float* out_b   = (const float*)d_in[10];
    float* out = (float*)d_out;

    gru_all<<<NBATCH / (NC * MT), 256, 0, stream>>>(z, labels, embed_w, fc_w, fc_b,
                                                    w_hh, b_ih, b_hh, out_w, out_b, out);
}

// Round 2
// 171.726 us; speedup vs baseline: 1.1056x; 1.1056x over previous
//
#include <hip/hip_runtime.h>

#define NB     8192
#define HDIM   64
#define SEQ    180
#define MT     16     // batch rows per block
#define SB     72     // bf16 LDS row stride: 144 B, 16B-aligned (SB=68 regressed: misaligned b128)
#define XSP    100    // xs prologue row stride (floats)

typedef __bf16 bf16x8 __attribute__((ext_vector_type(8)));
typedef __bf16 bf16x4 __attribute__((ext_vector_type(4)));
typedef float  f32x4  __attribute__((ext_vector_type(4)));

#define L2E 1.44269504088896340736f

__device__ __forceinline__ float tanh_f(float x) {
    float e = __builtin_amdgcn_exp2f((2.0f * L2E) * x);
    return 1.0f - 2.0f * __builtin_amdgcn_rcpf(1.0f + e);
}

#define MFMA __builtin_amdgcn_mfma_f32_16x16x32_bf16

// In-loop barrier: LDS-only drain. __syncthreads() would also wait vmcnt(0),
// serializing every step on the output-head global store ack (~100-300 cy)
// for no correctness reason (out[] is never read in-kernel; end-of-kernel
// release handles host visibility). lgkmcnt(0) covers the ds_write of the
// new state; "memory" clobber pins ds ops on the right side of the barrier.
#define BAR_LDS() asm volatile("s_waitcnt lgkmcnt(0)\n\ts_barrier" ::: "memory")

// R17 = R15 (proven 111.5us: transposed G^T = W·h^T, plain-bf16 W, fp32
// carry, packed epilogue, b64 state writes, all-wave redundant output head in
// the write shadow, 2 blocks/CU anti-phased) + relaxed in-loop barrier that
// does NOT drain vmcnt, letting the per-step global output stores float
// across barriers. R16's dual-chain/1-block-per-CU experiment regressed
// (lost 2-wave-per-SIMD TLP; single in-order wave can't out-issue two waves)
// and is fully reverted.
__global__ __launch_bounds__(256) void gru_all(
        const float* __restrict__ z, const int* __restrict__ labels,
        const float* __restrict__ embed_w, const float* __restrict__ fc_w,
        const float* __restrict__ fc_b, const float* __restrict__ w_hh,
        const float* __restrict__ b_ih, const float* __restrict__ b_hh,
        const float* __restrict__ out_w, const float* __restrict__ out_b,
        float* __restrict__ out) {
    __shared__ __align__(16) __bf16 hbuf[2][MT * SB];  // [buf] bf16(h)
    __shared__ __align__(16) float  xs[MT * XSP];      // h0 input [z|embed]

    const int t = threadIdx.x;
    const int w = t >> 6;          // wave 0..3
    const int l = t & 63;
    const int q = l >> 4;          // quad 0..3
    const int n16 = l & 15;
    const int jg = 16 * w + n16;   // W row this lane loads (A-frag m-index)
    const int jb = 16 * w + 4 * q; // first of the 4 h-cols this lane epilogues
    const int bbase = blockIdx.x * MT;

    // ---- prologue A: stage x = [z, embed(labels)] for 16 rows into LDS ----
    for (int c = t; c < MT * 24; c += 256) {    // 24 f32x4 chunks per row
        int m = c / 24, kk = (c % 24) * 4;
        f32x4 v;
        if (kk < 32) v = *(const f32x4*)(z + (size_t)(bbase + m) * 32 + kk);
        else         v = *(const f32x4*)(embed_w + labels[bbase + m] * 64 + (kk - 32));
        *(f32x4*)(xs + m * XSP + kk) = v;
    }

    // ---- persistent w_hh fragments, plain bf16 (MFMA A-operands) ----
    // A[m = n16][k = q*8+j + 32ks] = w_hh[g*64 + jg][k]
    bf16x8 whi[3][2];
#pragma unroll
    for (int g = 0; g < 3; ++g) {
        const float* pr = w_hh + (g * 64 + jg) * HDIM;
#pragma unroll
        for (int ks = 0; ks < 2; ++ks) {
            const float* p = pr + ks * 32 + q * 8;
            f32x4 va = *(const f32x4*)(p);
            f32x4 vb = *(const f32x4*)(p + 4);
#pragma unroll
            for (int j2 = 0; j2 < 4; ++j2) {
                whi[g][ks][j2]     = (__bf16)va[j2];
                whi[g][ks][4 + j2] = (__bf16)vb[j2];
            }
        }
    }

    // ---- output-head A fragments: A[m=n16][k] = out_w[n16][k] (n16<2 live) --
    bf16x8 obhi[2];
#pragma unroll
    for (int ks = 0; ks < 2; ++ks) {
        f32x4 va = {0.f, 0.f, 0.f, 0.f}, vb = {0.f, 0.f, 0.f, 0.f};
        if (n16 < 2) {
            va = *(const f32x4*)(out_w + n16 * 64 + ks * 32 + q * 8);
            vb = *(const f32x4*)(out_w + n16 * 64 + ks * 32 + q * 8 + 4);
        }
#pragma unroll
        for (int j2 = 0; j2 < 4; ++j2) {
            obhi[ks][j2]     = (__bf16)va[j2];
            obhi[ks][4 + j2] = (__bf16)vb[j2];
        }
    }
    // C/D bias by m-row (out-col): live rows m=0,1 sit at q==0, reg r=0,1
    const f32x4 obias = (q == 0) ? f32x4{out_b[0], out_b[1], 0.f, 0.f}
                                 : f32x4{0.f, 0.f, 0.f, 0.f};
    const f32x4 kZ = {0.f, 0.f, 0.f, 0.f};
    const f32x4 one4 = {1.f, 1.f, 1.f, 1.f};

    // every wave stores output for its 4 rows: q==0 lane, rows 4w..4w+3
    const bool ostorer = (q == 0) && ((n16 >> 2) == w);

    // per-lane gate constants: vectors over the lane's 4 cols jb..jb+3
    const f32x4 bihR = *(const f32x4*)(b_ih + jb);
    const f32x4 bhhR = *(const f32x4*)(b_hh + jb);
    const f32x4 bihZ = *(const f32x4*)(b_ih + 64 + jb);
    const f32x4 bhhZ = *(const f32x4*)(b_hh + 64 + jb);
    const f32x4 cR4 = (bihR + bhhR) * (-L2E);
    const f32x4 cZ4 = (bihZ + bhhZ) * (-L2E);
    const f32x4 bn4 = *(const f32x4*)(b_hh + 128 + jb);
    const f32x4 cN4 = (*(const f32x4*)(b_ih + 128 + jb)) * (2.0f * L2E);

    const int rdoff = n16 * SB + q * 8;    // h B-frag offset (16B-aligned)
    const int wboff = n16 * SB + jb;       // state-write offset (8B-aligned)
    float* opb = out + (size_t)(bbase + n16) * (SEQ * 2);  // this lane's row

    __syncthreads();   // xs ready

    // ---- prologue B: h0 = tanh(fc_b + fc_w . x); lane -> row n16, 4 cols ----
    f32x4 hprev;
    {
        f32x4 a = *(const f32x4*)(fc_b + jb);
        for (int kc = 0; kc < 24; ++kc) {
            f32x4 xv = *(const f32x4*)(xs + n16 * XSP + kc * 4);
#pragma unroll
            for (int r = 0; r < 4; ++r) {
                f32x4 wv = *(const f32x4*)(fc_w + (size_t)(jb + r) * 96 + kc * 4);
                a[r] += wv[0] * xv[0] + wv[1] * xv[1] + wv[2] * xv[2] + wv[3] * xv[3];
            }
        }
        bf16x4 hp;
#pragma unroll
        for (int r = 0; r < 4; ++r) {
            hprev[r] = tanh_f(a[r]);
            hp[r] = (__bf16)hprev[r];
        }
        *(bf16x4*)(hbuf[0] + wboff) = hp;   // one ds_write_b64
    }
    __syncthreads();   // state 0 published in buf 0

    // Anti-phase the two co-resident blocks (i and i+256 share a CU).
    if ((blockIdx.x >> 8) & 1) __builtin_amdgcn_s_sleep(8);

    for (int u = 0; u < SEQ / 4; ++u) {
#pragma unroll
        for (int s = 0; s < 4; ++s) {
            const int p = s & 1;
            const __bf16* Hh = hbuf[p];
            __bf16* Nh = hbuf[1 - p];

            // h B-frags of state i = 4u+s: B[k=q*8+j][n16] = h[n16][k]
            bf16x8 b0 = *(const bf16x8*)(Hh + rdoff);
            bf16x8 b1 = *(const bf16x8*)(Hh + rdoff + 32);

            // gates: G^T = W·h^T, 2-deep chain per gate
            f32x4 aR, aZ, aN;
            aR = MFMA(whi[0][0], b0, kZ, 0, 0, 0);
            aZ = MFMA(whi[1][0], b0, kZ, 0, 0, 0);
            aN = MFMA(whi[2][0], b0, kZ, 0, 0, 0);
            aR = MFMA(whi[0][1], b1, aR, 0, 0, 0);
            aZ = MFMA(whi[1][1], b1, aZ, 0, 0, 0);
            aN = MFMA(whi[2][1], b1, aN, 0, 0, 0);

            // epilogue: lane's 4 cols of row n16; non-trans math packed f32x4
            f32x4 tR = aR * (-L2E) + cR4;
            f32x4 tZ = aZ * (-L2E) + cZ4;
            f32x4 eR, eZ;
#pragma unroll
            for (int r = 0; r < 4; ++r) {
                eR[r] = __builtin_amdgcn_exp2f(tR[r]);
                eZ[r] = __builtin_amdgcn_exp2f(tZ[r]);
            }
            eR = eR + one4;
            eZ = eZ + one4;
            f32x4 rg, zg;
#pragma unroll
            for (int r = 0; r < 4; ++r) {
                rg[r] = __builtin_amdgcn_rcpf(eR[r]);
                zg[r] = __builtin_amdgcn_rcpf(eZ[r]);
            }
            f32x4 mm = aN + bn4;
            f32x4 tN = (rg * mm) * (2.0f * L2E) + cN4;
            f32x4 eN;
#pragma unroll
            for (int r = 0; r < 4; ++r) eN[r] = __builtin_amdgcn_exp2f(tN[r]);
            eN = eN + one4;
            f32x4 dd;
#pragma unroll
            for (int r = 0; r < 4; ++r) dd[r] = __builtin_amdgcn_rcpf(eN[r]);
            f32x4 ng = dd * (-2.0f) + one4;
            f32x4 hn = zg * (hprev - ng) + ng;   // exact fp32 carry
            hprev = hn;
            bf16x4 hp;
#pragma unroll
            for (int r = 0; r < 4; ++r) hp[r] = (__bf16)hn[r];
            *(bf16x4*)(Nh + wboff) = hp;         // one ds_write_b64

            // output head in the write-shadow: ALL waves compute (identical
            // streams -> no barrier straggler); each stores only its 4 rows.
            {
                f32x4 o = obias;
                o = MFMA(obhi[0], b0, o, 0, 0, 0);
                o = MFMA(obhi[1], b1, o, 0, 0, 0);
                if ((u | s) != 0 && ostorer)
                    *(float2*)(opb + (8 * u + 2 * s - 2)) = make_float2(o[0], o[1]);
            }

            BAR_LDS();   // state i+1 published (LDS-only drain; stores float)
        }
    }

    // final output: row 179 from state 180 (in buf 0)
    {
        const __bf16* Hh = hbuf[0];
        bf16x8 b0 = *(const bf16x8*)(Hh + rdoff);
        bf16x8 b1 = *(const bf16x8*)(Hh + rdoff + 32);
        f32x4 o = obias;
        o = MFMA(obhi[0], b0, o, 0, 0, 0);
        o = MFMA(obhi[1], b1, o, 0, 0, 0);
        if (ostorer)
            *(float2*)(opb + (SEQ - 1) * 2) = make_float2(o[0], o[1]);
    }
}

extern "C" void kernel_launch(void* const* d_in, const int* in_sizes, int n_in,
                              void* d_out, int out_size, void* d_ws, size_t ws_size,
                              hipStream_t stream) {
    (void)in_sizes; (void)n_in; (void)out_size; (void)d_ws; (void)ws_size;
    const float* z       = (const float*)d_in[0];
    const int*   labels  = (const int*)d_in[1];
    const float* embed_w = (const float*)d_in[2];
    const float* fc_w    = (const float*)d_in[3];
    const float* fc_b    = (const float*)d_in[4];
    // d_in[5] = w_ih: unused (GRU input is all zeros; b_ih carries the effect)
    const float* w_hh    = (const float*)d_in[6];
    const float* b_ih    = (const float*)d_in[7];
    const float* b_hh    = (const float*)d_in[8];
    const float* out_w   = (const float*)d_in[9];
    const float* out_b   = (const float*)d_in[10];
    float* out = (float*)d_out;

    gru_all<<<NB / MT, 256, 0, stream>>>(z, labels, embed_w, fc_w, fc_b,
                                         w_hh, b_ih, b_hh, out_w, out_b, out);
}

// Round 3
// 165.320 us; speedup vs baseline: 1.1485x; 1.0387x over previous
//
#include <hip/hip_runtime.h>

#define NB     8192
#define HDIM   64
#define SEQ    180
#define MT     16     // batch rows per block
#define SB     72     // bf16 LDS row stride: 144 B, 16B-aligned (SB=68 regressed: misaligned b128)
#define XSP    100    // xs prologue row stride (floats)

typedef __bf16 bf16x8 __attribute__((ext_vector_type(8)));
typedef __bf16 bf16x4 __attribute__((ext_vector_type(4)));
typedef float  f32x4  __attribute__((ext_vector_type(4)));

#define L2E 1.44269504088896340736f

__device__ __forceinline__ float tanh_f(float x) {
    float e = __builtin_amdgcn_exp2f((2.0f * L2E) * x);
    return 1.0f - 2.0f * __builtin_amdgcn_rcpf(1.0f + e);
}

#define MFMA __builtin_amdgcn_mfma_f32_16x16x32_bf16

// In-loop barrier: LDS-only drain (R17: proven neutral vs __syncthreads, kept
// because the deferred head store now floats across barriers by design).
#define BAR_LDS() asm volatile("s_waitcnt lgkmcnt(0)\n\ts_barrier" ::: "memory")

// R18 = R17 + two per-step cuts:
//  (1) fused epilogue algebra: h' = [h*(eN+1) + eZ*(eN-1)] / [(eN+1)(1+eZ)]
//      -- one rcp replaces zg's and tanh's rcps (6 -> 5 trans/element).
//      Overflow-safe: |preact| <= ~8.4 with these weight scales, so
//      D* = (eN+1)(1+eZ) <= ~6e10 << f32 max.
//  (2) deferred output head: previous step's b-frags (pb0/pb1, free register
//      renaming under the 4x unroll) feed the 2 head MFMAs AFTER the barrier,
//      filling the ds_read lgkm-wait shadow instead of lengthening the
//      pre-barrier path of 4 lockstep waves. Loop tail emits rows 178+179.
__global__ __launch_bounds__(256) void gru_all(
        const float* __restrict__ z, const int* __restrict__ labels,
        const float* __restrict__ embed_w, const float* __restrict__ fc_w,
        const float* __restrict__ fc_b, const float* __restrict__ w_hh,
        const float* __restrict__ b_ih, const float* __restrict__ b_hh,
        const float* __restrict__ out_w, const float* __restrict__ out_b,
        float* __restrict__ out) {
    __shared__ __align__(16) __bf16 hbuf[2][MT * SB];  // [buf] bf16(h)
    __shared__ __align__(16) float  xs[MT * XSP];      // h0 input [z|embed]

    const int t = threadIdx.x;
    const int w = t >> 6;          // wave 0..3
    const int l = t & 63;
    const int q = l >> 4;          // quad 0..3
    const int n16 = l & 15;
    const int jg = 16 * w + n16;   // W row this lane loads (A-frag m-index)
    const int jb = 16 * w + 4 * q; // first of the 4 h-cols this lane epilogues
    const int bbase = blockIdx.x * MT;

    // ---- prologue A: stage x = [z, embed(labels)] for 16 rows into LDS ----
    for (int c = t; c < MT * 24; c += 256) {    // 24 f32x4 chunks per row
        int m = c / 24, kk = (c % 24) * 4;
        f32x4 v;
        if (kk < 32) v = *(const f32x4*)(z + (size_t)(bbase + m) * 32 + kk);
        else         v = *(const f32x4*)(embed_w + labels[bbase + m] * 64 + (kk - 32));
        *(f32x4*)(xs + m * XSP + kk) = v;
    }

    // ---- persistent w_hh fragments, plain bf16 (MFMA A-operands) ----
    // A[m = n16][k = q*8+j + 32ks] = w_hh[g*64 + jg][k]
    bf16x8 whi[3][2];
#pragma unroll
    for (int g = 0; g < 3; ++g) {
        const float* pr = w_hh + (g * 64 + jg) * HDIM;
#pragma unroll
        for (int ks = 0; ks < 2; ++ks) {
            const float* p = pr + ks * 32 + q * 8;
            f32x4 va = *(const f32x4*)(p);
            f32x4 vb = *(const f32x4*)(p + 4);
#pragma unroll
            for (int j2 = 0; j2 < 4; ++j2) {
                whi[g][ks][j2]     = (__bf16)va[j2];
                whi[g][ks][4 + j2] = (__bf16)vb[j2];
            }
        }
    }

    // ---- output-head A fragments: A[m=n16][k] = out_w[n16][k] (n16<2 live) --
    bf16x8 obhi[2];
#pragma unroll
    for (int ks = 0; ks < 2; ++ks) {
        f32x4 va = {0.f, 0.f, 0.f, 0.f}, vb = {0.f, 0.f, 0.f, 0.f};
        if (n16 < 2) {
            va = *(const f32x4*)(out_w + n16 * 64 + ks * 32 + q * 8);
            vb = *(const f32x4*)(out_w + n16 * 64 + ks * 32 + q * 8 + 4);
        }
#pragma unroll
        for (int j2 = 0; j2 < 4; ++j2) {
            obhi[ks][j2]     = (__bf16)va[j2];
            obhi[ks][4 + j2] = (__bf16)vb[j2];
        }
    }
    // C/D bias by m-row (out-col): live rows m=0,1 sit at q==0, reg r=0,1
    const f32x4 obias = (q == 0) ? f32x4{out_b[0], out_b[1], 0.f, 0.f}
                                 : f32x4{0.f, 0.f, 0.f, 0.f};
    const f32x4 kZ = {0.f, 0.f, 0.f, 0.f};
    const f32x4 one4 = {1.f, 1.f, 1.f, 1.f};

    // every wave stores output for its 4 rows: q==0 lane, rows 4w..4w+3
    const bool ostorer = (q == 0) && ((n16 >> 2) == w);

    // per-lane gate constants: vectors over the lane's 4 cols jb..jb+3
    const f32x4 bihR = *(const f32x4*)(b_ih + jb);
    const f32x4 bhhR = *(const f32x4*)(b_hh + jb);
    const f32x4 bihZ = *(const f32x4*)(b_ih + 64 + jb);
    const f32x4 bhhZ = *(const f32x4*)(b_hh + 64 + jb);
    const f32x4 cR4 = (bihR + bhhR) * (-L2E);
    const f32x4 cZ4 = (bihZ + bhhZ) * (-L2E);
    const f32x4 bn4 = *(const f32x4*)(b_hh + 128 + jb);
    const f32x4 cN4 = (*(const f32x4*)(b_ih + 128 + jb)) * (2.0f * L2E);

    const int rdoff = n16 * SB + q * 8;    // h B-frag offset (16B-aligned)
    const int wboff = n16 * SB + jb;       // state-write offset (8B-aligned)
    float* opb = out + (size_t)(bbase + n16) * (SEQ * 2);  // this lane's row

    __syncthreads();   // xs ready

    // ---- prologue B: h0 = tanh(fc_b + fc_w . x); lane -> row n16, 4 cols ----
    f32x4 hprev;
    {
        f32x4 a = *(const f32x4*)(fc_b + jb);
        for (int kc = 0; kc < 24; ++kc) {
            f32x4 xv = *(const f32x4*)(xs + n16 * XSP + kc * 4);
#pragma unroll
            for (int r = 0; r < 4; ++r) {
                f32x4 wv = *(const f32x4*)(fc_w + (size_t)(jb + r) * 96 + kc * 4);
                a[r] += wv[0] * xv[0] + wv[1] * xv[1] + wv[2] * xv[2] + wv[3] * xv[3];
            }
        }
        bf16x4 hp;
#pragma unroll
        for (int r = 0; r < 4; ++r) {
            hprev[r] = tanh_f(a[r]);
            hp[r] = (__bf16)hprev[r];
        }
        *(bf16x4*)(hbuf[0] + wboff) = hp;   // one ds_write_b64
    }
    __syncthreads();   // state 0 published in buf 0

    // Anti-phase the two co-resident blocks (i and i+256 share a CU).
    if ((blockIdx.x >> 8) & 1) __builtin_amdgcn_s_sleep(8);

    // previous step's b-frags for the deferred head (garbage first 2 iters;
    // computed unconditionally for wave balance, store is predicated)
    bf16x8 pb0 = {}, pb1 = {};

    for (int u = 0; u < SEQ / 4; ++u) {
#pragma unroll
        for (int s = 0; s < 4; ++s) {
            const int p = s & 1;
            const __bf16* Hh = hbuf[p];
            __bf16* Nh = hbuf[1 - p];

            // h B-frags of state i = 4u+s: B[k=q*8+j][n16] = h[n16][k]
            bf16x8 b0 = *(const bf16x8*)(Hh + rdoff);
            bf16x8 b1 = *(const bf16x8*)(Hh + rdoff + 32);

            // deferred output head (state i-1 -> out row i-2): register-only
            // MFMAs fill the ds_read lgkm-wait shadow right after the barrier
            {
                f32x4 o = obias;
                o = MFMA(obhi[0], pb0, o, 0, 0, 0);
                o = MFMA(obhi[1], pb1, o, 0, 0, 0);
                if ((u > 0 || s >= 2) && ostorer)
                    *(float2*)(opb + (8 * u + 2 * s - 4)) = make_float2(o[0], o[1]);
            }

            // gates: G^T = W·h^T, 2-deep chain per gate
            f32x4 aR, aZ, aN;
            aR = MFMA(whi[0][0], b0, kZ, 0, 0, 0);
            aZ = MFMA(whi[1][0], b0, kZ, 0, 0, 0);
            aN = MFMA(whi[2][0], b0, kZ, 0, 0, 0);
            aR = MFMA(whi[0][1], b1, aR, 0, 0, 0);
            aZ = MFMA(whi[1][1], b1, aZ, 0, 0, 0);
            aN = MFMA(whi[2][1], b1, aN, 0, 0, 0);

            // fused epilogue: eR,eZ,eN + rg rcp + ONE combined rcp.
            // h' = [h*(eN+1) + eZ*(eN-1)] / [(eN+1)(1+eZ)]
            f32x4 tR = aR * (-L2E) + cR4;
            f32x4 tZ = aZ * (-L2E) + cZ4;
            f32x4 eR, eZ;
#pragma unroll
            for (int r = 0; r < 4; ++r) {
                eR[r] = __builtin_amdgcn_exp2f(tR[r]);
                eZ[r] = __builtin_amdgcn_exp2f(tZ[r]);
            }
            f32x4 A = eR + one4;
            f32x4 rg;
#pragma unroll
            for (int r = 0; r < 4; ++r) rg[r] = __builtin_amdgcn_rcpf(A[r]);
            f32x4 mm = aN + bn4;
            f32x4 tN = (rg * mm) * (2.0f * L2E) + cN4;
            f32x4 eN;
#pragma unroll
            for (int r = 0; r < 4; ++r) eN[r] = __builtin_amdgcn_exp2f(tN[r]);
            f32x4 wz = eZ + one4;            // 1 + eZ
            f32x4 pz = eZ + hprev;           // eZ + h
            f32x4 qz = hprev - eZ;           // h - eZ
            f32x4 Nst = eN * pz + qz;        // h*(eN+1) + eZ*(eN-1)
            f32x4 Dst = eN * wz + wz;        // (eN+1)*(1+eZ)
            f32x4 rD;
#pragma unroll
            for (int r = 0; r < 4; ++r) rD[r] = __builtin_amdgcn_rcpf(Dst[r]);
            f32x4 hn = Nst * rD;             // exact fp32 carry
            hprev = hn;
            bf16x4 hp;
#pragma unroll
            for (int r = 0; r < 4; ++r) hp[r] = (__bf16)hn[r];
            *(bf16x4*)(Nh + wboff) = hp;     // one ds_write_b64

            pb0 = b0; pb1 = b1;              // renamed, not copied (unroll 4)

            BAR_LDS();   // state i+1 published (LDS-only drain; stores float)
        }
    }

    // tail: deferred head of state 179 (pb) -> row 178, then state 180 -> 179
    {
        f32x4 o = obias;
        o = MFMA(obhi[0], pb0, o, 0, 0, 0);
        o = MFMA(obhi[1], pb1, o, 0, 0, 0);
        if (ostorer)
            *(float2*)(opb + (SEQ - 2) * 2) = make_float2(o[0], o[1]);

        const __bf16* Hh = hbuf[0];
        bf16x8 b0 = *(const bf16x8*)(Hh + rdoff);
        bf16x8 b1 = *(const bf16x8*)(Hh + rdoff + 32);
        f32x4 o2 = obias;
        o2 = MFMA(obhi[0], b0, o2, 0, 0, 0);
        o2 = MFMA(obhi[1], b1, o2, 0, 0, 0);
        if (ostorer)
            *(float2*)(opb + (SEQ - 1) * 2) = make_float2(o2[0], o2[1]);
    }
}

extern "C" void kernel_launch(void* const* d_in, const int* in_sizes, int n_in,
                              void* d_out, int out_size, void* d_ws, size_t ws_size,
                              hipStream_t stream) {
    (void)in_sizes; (void)n_in; (void)out_size; (void)d_ws; (void)ws_size;
    const float* z       = (const float*)d_in[0];
    const int*   labels  = (const int*)d_in[1];
    const float* embed_w = (const float*)d_in[2];
    const float* fc_w    = (const float*)d_in[3];
    const float* fc_b    = (const float*)d_in[4];
    // d_in[5] = w_ih: unused (GRU input is all zeros; b_ih carries the effect)
    const float* w_hh    = (const float*)d_in[6];
    const float* b_ih    = (const float*)d_in[7];
    const float* b_hh    = (const float*)d_in[8];
    const float* out_w   = (const float*)d_in[9];
    const float* out_b   = (const float*)d_in[10];
    float* out = (float*)d_out;

    gru_all<<<NB / MT, 256, 0, stream>>>(z, labels, embed_w, fc_w, fc_b,
                                         w_hh, b_ih, b_hh, out_w, out_b, out);
}